// Round 6
// baseline (1509.363 us; speedup 1.0000x reference)
//
#include <hip/hip_runtime.h>
#include <math.h>

// SoftSkeletonize via the erosion-chain identity:
//   e_0 = img, e_{i+1} = erode(e_i)      (erode = 5-pt cross min, +inf pad)
//   delta_i = relu(e_i - dilate3x3(e_{i+1}))            (dilate pad = -inf)
//   skel: s = delta_0; s += relu(delta_i - s*delta_i), i = 1..40
//
// 5 fused phases (S = 9,8,8,8,8). Per 64x64 tile, stage e + halo in LDS,
// run S+1 merged passes (pass t: erode e_{t-1}->e_t; delta_{t-2} from
// dilate(e_{t-1}) and e_{t-2} read from dst buffer before own overwrite).
//
// Round-6 layout (conflict-free by construction):
//  - STRD = 96 floats (24 quads, divisible by 8): every aligned 8-lane group
//    covers 8 consecutive bank-quads of ONE row -> all b128 reads/writes and
//    all +/-1-quad shifted reads are exactly conflict-free (round-5's
//    STRD=88 wrapped mid-group at row ends -> 2-way repeats, ~30% cycles).
//  - Edge scalars via ds_read_b32 (banks 4c-1 / 4c+4 distinct mod 32), not
//    full edge quads: erode = 6 b128 + 8 b32 per 4-row patch.
//  - 4-row patches, NT=576: erode grid 22x22 fits one round.
// Geometry: MTR=13 (central rows ghb = h0+4p-12 align to patch base), RH=90.
// Validity: e_j good on buffer rows [j,89-j] x cols [j,87-j]; consumed
// region at j=S=9 is rows [12,77] x cols [11,77]  -> inside. LDS front/back
// pad absorbs the o-STRD-1 underflow at c=0 (values never consumed).

#define HH 1024
#define WW 1024
#define T 64
#define MTR 13                 // top row margin (central rows = buf rows 13..76)
#define MTC 12                 // left col margin (central quads 3..18)
#define RH 90                  // buffer rows
#define STq 24                 // quads per row (multiple of 8!)
#define STRD 96                // floats per row
#define NT 576                 // 9 waves
#define PADF 4

#define LD4(p)    (*(const float4*)(p))
#define ST4(p, v) (*(float4*)(p) = (v))

__device__ __forceinline__ float relu_(float x) { return x > 0.f ? x : 0.f; }
__device__ __forceinline__ float4 min4_(float4 a, float4 b) {
    return make_float4(fminf(a.x,b.x), fminf(a.y,b.y), fminf(a.z,b.z), fminf(a.w,b.w));
}
__device__ __forceinline__ float4 max4_(float4 a, float4 b) {
    return make_float4(fmaxf(a.x,b.x), fmaxf(a.y,b.y), fmaxf(a.z,b.z), fmaxf(a.w,b.w));
}
__device__ __forceinline__ float4 hmin4(float L, float4 a, float R) {
    float4 h;
    h.x = fminf(L,   fminf(a.x, a.y)); h.y = fminf(a.x, fminf(a.y, a.z));
    h.z = fminf(a.y, fminf(a.z, a.w)); h.w = fminf(a.z, fminf(a.w, R));
    return h;
}
__device__ __forceinline__ float4 hmax4(float L, float4 a, float R) {
    float4 h;
    h.x = fmaxf(L,   fmaxf(a.x, a.y)); h.y = fmaxf(a.x, fmaxf(a.y, a.z));
    h.z = fmaxf(a.y, fmaxf(a.z, a.w)); h.w = fmaxf(a.z, fmaxf(a.w, R));
    return h;
}
__device__ __forceinline__ float4 dmask4(float4 v, float rm, float4 cm) {
    // rm/cm = +INF if in-image, -INF outside -> out cells become -INF
    float4 o;
    o.x = fminf(fminf(v.x, cm.x), rm); o.y = fminf(fminf(v.y, cm.y), rm);
    o.z = fminf(fminf(v.z, cm.z), rm); o.w = fminf(fminf(v.w, cm.w), rm);
    return o;
}
__device__ __forceinline__ void skup(float4& s, float4 e, float4 d, bool init) {
    float4 dl;
    dl.x = relu_(e.x - d.x); dl.y = relu_(e.y - d.y);
    dl.z = relu_(e.z - d.z); dl.w = relu_(e.w - d.w);
    if (init) { s = dl; }
    else {
        s.x += relu_(dl.x - s.x * dl.x); s.y += relu_(dl.y - s.y * dl.y);
        s.z += relu_(dl.z - s.z * dl.z); s.w += relu_(dl.w - s.w * dl.w);
    }
}

__global__ __launch_bounds__(NT) void phase_kernel(
    const float* __restrict__ src, float* __restrict__ dst,
    float* __restrict__ skel, int S, int first, int last)
{
    __shared__ __align__(16) float b0_[PADF + RH * STRD + PADF];
    __shared__ __align__(16) float b1_[PADF + RH * STRD + PADF];
    float* buf0 = b0_ + PADF;
    float* buf1 = b1_ + PADF;

    const int h0 = blockIdx.y * T;
    const int w0 = blockIdx.x * T;
    const size_t plane = (size_t)HH * WW;
    const float* sp = src + blockIdx.z * plane;
    float* skp = skel + blockIdx.z * plane;
    float* dp = dst ? dst + blockIdx.z * plane : nullptr;

    const int tid = threadIdx.x;
    const bool border = (h0 == 0) || (w0 == 0) || (h0 + T == HH) || (w0 + T == WW);

    // ---- stage e_{i0} (+inf outside image) into buf0
    if (!border) {
        const float* base = sp + (size_t)(h0 - MTR) * WW + (w0 - MTC);
        for (int i = tid; i < RH * STq; i += NT) {
            int r = i / STq, q = i - r * STq;
            ST4(&buf0[r * STRD + 4 * q], LD4(base + (size_t)r * WW + 4 * q));
        }
    } else {
        for (int i = tid; i < RH * STRD; i += NT) {
            int r = i / STRD, c = i - r * STRD;
            int gh = h0 - MTR + r, gw = w0 - MTC + c;
            float v = INFINITY;
            if ((unsigned)gh < HH && (unsigned)gw < WW) v = sp[(size_t)gh * WW + gw];
            buf0[r * STRD + c] = v;
        }
    }

    // ---- geometry: 4-row x 1-quad patches, rows 1+4p..4+4p, quad c
    const int p = tid / STq, c = tid - STq * p;
    const bool act = (p < 22) && (c < 22);
    const int o = (1 + 4 * p) * STRD + 4 * c;
    const bool cen = act && (p >= 3) && (p <= 18) && (c >= 3) && (c <= 18);
    const int ghb = h0 - MTR + 1 + 4 * p;   // image row of patch row 0
    const int gwb = w0 - MTC + 4 * c;       // image col of quad start

    float4 s0 = make_float4(0,0,0,0), s1 = s0, s2 = s0, s3 = s0;
    if (!first && cen) {
        const float* g = skp + (size_t)ghb * WW + gwb;
        s0 = LD4(g); s1 = LD4(g + WW); s2 = LD4(g + 2 * WW); s3 = LD4(g + 3 * WW);
    }
    __syncthreads();

    for (int t = 1; t <= S + 1; ++t) {
        float* sb = ((t - 1) & 1) ? buf1 : buf0;
        float* db = (t & 1) ? buf1 : buf0;
        const bool do_er = (t <= S);
        const bool do_dl = (t >= 2);
        const bool init = (first != 0) && (t == 2);
        const bool cw = cen && do_dl;
        if (act && (do_er || cw)) {
            // quad reads: rows -1..+4 relative to patch
            float4 U  = LD4(sb + o - STRD);
            float4 A0 = LD4(sb + o);
            float4 A1 = LD4(sb + o + STRD);
            float4 A2 = LD4(sb + o + 2 * STRD);
            float4 A3 = LD4(sb + o + 3 * STRD);
            float4 Dq = LD4(sb + o + 4 * STRD);
            // edge scalars (b32, conflict-free): col-1 (.w of left), col+4 (.x of right)
            float L0 = sb[o - 1],            R0 = sb[o + 4];
            float L1 = sb[o + STRD - 1],     R1 = sb[o + STRD + 4];
            float L2 = sb[o + 2 * STRD - 1], R2 = sb[o + 2 * STRD + 4];
            float L3 = sb[o + 3 * STRD - 1], R3 = sb[o + 3 * STRD + 4];
            float4 ec0, ec1, ec2, ec3;
            float eUL, eUR, eDL, eDR;
            if (cw) {   // dilate extras + e_{t-2} own quads (read BEFORE own store)
                eUL = sb[o - STRD - 1];     eUR = sb[o - STRD + 4];
                eDL = sb[o + 4 * STRD - 1]; eDR = sb[o + 4 * STRD + 4];
                ec0 = LD4(db + o);              ec1 = LD4(db + o + STRD);
                ec2 = LD4(db + o + 2 * STRD);   ec3 = LD4(db + o + 3 * STRD);
            }
            if (do_er) {
                float4 e0 = min4_(min4_(U,  A1), hmin4(L0, A0, R0));
                float4 e1 = min4_(min4_(A0, A2), hmin4(L1, A1, R1));
                float4 e2 = min4_(min4_(A1, A3), hmin4(L2, A2, R2));
                float4 e3 = min4_(min4_(A2, Dq), hmin4(L3, A3, R3));
                if (border) {   // force +inf at out-of-image outputs
                    float4 cwm;
                    cwm.x = (unsigned)(gwb + 0) < WW ? -INFINITY : INFINITY;
                    cwm.y = (unsigned)(gwb + 1) < WW ? -INFINITY : INFINITY;
                    cwm.z = (unsigned)(gwb + 2) < WW ? -INFINITY : INFINITY;
                    cwm.w = (unsigned)(gwb + 3) < WW ? -INFINITY : INFINITY;
                    float r0 = (unsigned)(ghb + 0) < HH ? -INFINITY : INFINITY;
                    float r1 = (unsigned)(ghb + 1) < HH ? -INFINITY : INFINITY;
                    float r2 = (unsigned)(ghb + 2) < HH ? -INFINITY : INFINITY;
                    float r3 = (unsigned)(ghb + 3) < HH ? -INFINITY : INFINITY;
                    e0 = max4_(e0, max4_(make_float4(r0, r0, r0, r0), cwm));
                    e1 = max4_(e1, max4_(make_float4(r1, r1, r1, r1), cwm));
                    e2 = max4_(e2, max4_(make_float4(r2, r2, r2, r2), cwm));
                    e3 = max4_(e3, max4_(make_float4(r3, r3, r3, r3), cwm));
                }
                ST4(db + o, e0);            ST4(db + o + STRD, e1);
                ST4(db + o + 2 * STRD, e2); ST4(db + o + 3 * STRD, e3);
            }
            if (cw) {
                float4 tU = U, t0 = A0, t1 = A1, t2 = A2, t3 = A3, tD = Dq;
                float lU = eUL, rU = eUR, l0 = L0, r0s = R0, l1 = L1, r1s = R1;
                float l2 = L2, r2s = R2, l3 = L3, r3s = R3, lD = eDL, rD = eDR;
                if (border) {   // mask inputs to -inf outside image
                    float rmU = (unsigned)(ghb - 1) < HH ? INFINITY : -INFINITY;
                    float rm0 = (unsigned)(ghb + 0) < HH ? INFINITY : -INFINITY;
                    float rm1 = (unsigned)(ghb + 1) < HH ? INFINITY : -INFINITY;
                    float rm2 = (unsigned)(ghb + 2) < HH ? INFINITY : -INFINITY;
                    float rm3 = (unsigned)(ghb + 3) < HH ? INFINITY : -INFINITY;
                    float rmD = (unsigned)(ghb + 4) < HH ? INFINITY : -INFINITY;
                    float cmL = (unsigned)(gwb - 1) < WW ? INFINITY : -INFINITY;
                    float cmR = (unsigned)(gwb + 4) < WW ? INFINITY : -INFINITY;
                    float4 cmC;
                    cmC.x = (unsigned)(gwb + 0) < WW ? INFINITY : -INFINITY;
                    cmC.y = (unsigned)(gwb + 1) < WW ? INFINITY : -INFINITY;
                    cmC.z = (unsigned)(gwb + 2) < WW ? INFINITY : -INFINITY;
                    cmC.w = (unsigned)(gwb + 3) < WW ? INFINITY : -INFINITY;
                    tU = dmask4(tU, rmU, cmC); t0 = dmask4(t0, rm0, cmC);
                    t1 = dmask4(t1, rm1, cmC); t2 = dmask4(t2, rm2, cmC);
                    t3 = dmask4(t3, rm3, cmC); tD = dmask4(tD, rmD, cmC);
                    lU = fminf(fminf(lU, cmL), rmU); rU = fminf(fminf(rU, cmR), rmU);
                    l0 = fminf(fminf(l0, cmL), rm0); r0s = fminf(fminf(r0s, cmR), rm0);
                    l1 = fminf(fminf(l1, cmL), rm1); r1s = fminf(fminf(r1s, cmR), rm1);
                    l2 = fminf(fminf(l2, cmL), rm2); r2s = fminf(fminf(r2s, cmR), rm2);
                    l3 = fminf(fminf(l3, cmL), rm3); r3s = fminf(fminf(r3s, cmR), rm3);
                    lD = fminf(fminf(lD, cmL), rmD); rD = fminf(fminf(rD, cmR), rmD);
                }
                float4 hU = hmax4(lU, tU, rU);
                float4 h0 = hmax4(l0, t0, r0s);
                float4 h1 = hmax4(l1, t1, r1s);
                float4 h2 = hmax4(l2, t2, r2s);
                float4 h3 = hmax4(l3, t3, r3s);
                float4 hD = hmax4(lD, tD, rD);
                float4 d0 = max4_(hU, max4_(h0, h1));
                float4 d1 = max4_(h0, max4_(h1, h2));
                float4 d2 = max4_(h1, max4_(h2, h3));
                float4 d3 = max4_(h2, max4_(h3, hD));
                skup(s0, ec0, d0, init); skup(s1, ec1, d1, init);
                skup(s2, ec2, d2, init); skup(s3, ec3, d3, init);
            }
        }
        __syncthreads();
    }

    // ---- writeback: skel always; e_S central if not last phase
    const float* eb = (S & 1) ? buf1 : buf0;
    if (cen) {
        float* g = skp + (size_t)ghb * WW + gwb;
        ST4(g, s0); ST4(g + WW, s1); ST4(g + 2 * WW, s2); ST4(g + 3 * WW, s3);
        if (!last) {
            float* gd = dp + (size_t)ghb * WW + gwb;
            ST4(gd, LD4(eb + o));
            ST4(gd + WW, LD4(eb + o + STRD));
            ST4(gd + 2 * WW, LD4(eb + o + 2 * STRD));
            ST4(gd + 3 * WW, LD4(eb + o + 3 * STRD));
        }
    }
}

extern "C" void kernel_launch(void* const* d_in, const int* in_sizes, int n_in,
                              void* d_out, int out_size, void* d_ws, size_t ws_size,
                              hipStream_t stream) {
    const float* img = (const float*)d_in[0];
    float* skel = (float*)d_out;
    const int B = in_sizes[0] / (HH * WW);  // 16
    const size_t plane = (size_t)HH * WW;

    float* e0 = (float*)d_ws;
    float* e1 = e0 + (size_t)B * plane;

    dim3 grid(WW / T, HH / T, B);
    dim3 block(NT);

    const int Ks[5] = {9, 8, 8, 8, 8};   // 41 deltas total (init + 40 iters)
    const float* src = img;
    float* ebufs[2] = {e0, e1};
    for (int p = 0; p < 5; ++p) {
        int first = (p == 0), last = (p == 4);
        float* dstp = last ? nullptr : ebufs[p & 1];
        phase_kernel<<<grid, block, 0, stream>>>(src, dstp, skel, Ks[p], first, last);
        src = dstp;
    }
}

// Round 7
// 1054.007 us; speedup vs baseline: 1.4320x; 1.4320x over previous
//
#include <hip/hip_runtime.h>
#include <math.h>

// SoftSkeletonize via the erosion-chain identity:
//   e_0 = img, e_{i+1} = erode(e_i)      (erode = 5-pt cross min, +inf pad)
//   delta_i = relu(e_i - dilate3x3(e_{i+1}))            (dilate pad = -inf)
//   skel: s = delta_0; s += relu(delta_i - s*delta_i), i = 1..40
//
// 5 fused phases (S = 9,8,8,8,8). Per 64x64 tile, stage e + halo in LDS,
// S+1 merged passes (pass t: erode e_{t-1}->e_t; delta_{t-2} from
// dilate(e_{t-1}); e_{t-2} comes from a prev1/prev2 REGISTER rotation --
// the thread's own erode output two passes ago -- no LDS read needed).
//
// Conflict-free layout (fixes r5's 30% and r6's b32 8-way):
//  - STRD = 96 floats = 24 quads (== 0 mod 8) and thread map c = idx % 24:
//    aligned 8-lane groups start at c in {0,8,16} and NEVER straddle a row;
//    every b128 access (incl. +/-1-quad shifted edge reads) covers 8
//    consecutive bank-quads -> exactly conflict-free.
//  - NO b32 edge reads (r6's (4c-1) mod 32 hit only 8 banks -> 8-way).
//  - 2-row patches, 2 rounds, NT=512 (r5 structure: best latency hiding).
// Geometry: MTR=11, MTC=12, RH=86. Erode computes rows 1..84 x quads 0..21.
// Validity: e_j rows [j,85-j] cols [j,88-j] superset of consumed [10,75] x
// [11,76] at j<=9. Front/back 4-float pad absorbs o-STRD-4 underflow at c=0.

#define HH 1024
#define WW 1024
#define T 64
#define MTR 11                 // top row margin (central rows = buf rows 11..74)
#define MTC 12                 // left col margin (central quads 3..18)
#define RH 86                  // buffer rows
#define STq 24                 // quads per row (multiple of 8!)
#define STRD 96                // floats per row
#define NT 512
#define PADF 4

#define LD4(p)    (*(const float4*)(p))
#define ST4(p, v) (*(float4*)(p) = (v))

__device__ __forceinline__ float relu_(float x) { return x > 0.f ? x : 0.f; }
__device__ __forceinline__ float4 min4_(float4 a, float4 b) {
    return make_float4(fminf(a.x,b.x), fminf(a.y,b.y), fminf(a.z,b.z), fminf(a.w,b.w));
}
__device__ __forceinline__ float4 max4_(float4 a, float4 b) {
    return make_float4(fmaxf(a.x,b.x), fmaxf(a.y,b.y), fmaxf(a.z,b.z), fmaxf(a.w,b.w));
}
__device__ __forceinline__ float4 hmin4(float L, float4 a, float R) {
    float4 h;
    h.x = fminf(L,   fminf(a.x, a.y)); h.y = fminf(a.x, fminf(a.y, a.z));
    h.z = fminf(a.y, fminf(a.z, a.w)); h.w = fminf(a.z, fminf(a.w, R));
    return h;
}
__device__ __forceinline__ float4 hmax4(float L, float4 a, float R) {
    float4 h;
    h.x = fmaxf(L,   fmaxf(a.x, a.y)); h.y = fmaxf(a.x, fmaxf(a.y, a.z));
    h.z = fmaxf(a.y, fmaxf(a.z, a.w)); h.w = fmaxf(a.z, fmaxf(a.w, R));
    return h;
}
__device__ __forceinline__ float4 dmask4(float4 v, float rm, float4 cm) {
    float4 o;
    o.x = fminf(fminf(v.x, cm.x), rm); o.y = fminf(fminf(v.y, cm.y), rm);
    o.z = fminf(fminf(v.z, cm.z), rm); o.w = fminf(fminf(v.w, cm.w), rm);
    return o;
}
__device__ __forceinline__ void skup(float4& s, float4 e, float4 d, bool init) {
    float4 dl;
    dl.x = relu_(e.x - d.x); dl.y = relu_(e.y - d.y);
    dl.z = relu_(e.z - d.z); dl.w = relu_(e.w - d.w);
    if (init) { s = dl; }
    else {
        s.x += relu_(dl.x - s.x * dl.x); s.y += relu_(dl.y - s.y * dl.y);
        s.z += relu_(dl.z - s.z * dl.z); s.w += relu_(dl.w - s.w * dl.w);
    }
}

__global__ __launch_bounds__(NT, 4) void phase_kernel(
    const float* __restrict__ src, float* __restrict__ dst,
    float* __restrict__ skel, int S, int first, int last)
{
    __shared__ __align__(16) float b0_[PADF + RH * STRD + PADF];
    __shared__ __align__(16) float b1_[PADF + RH * STRD + PADF];
    float* buf0 = b0_ + PADF;
    float* buf1 = b1_ + PADF;

    const int h0 = blockIdx.y * T;
    const int w0 = blockIdx.x * T;
    const size_t plane = (size_t)HH * WW;
    const float* sp = src + blockIdx.z * plane;
    float* skp = skel + blockIdx.z * plane;
    float* dp = dst ? dst + blockIdx.z * plane : nullptr;

    const int tid = threadIdx.x;
    const bool border = (h0 == 0) || (w0 == 0) || (h0 + T == HH) || (w0 + T == WW);

    // ---- stage e_{i0} (+inf outside image) into buf0 (full 96 cols)
    if (!border) {
        const float* base = sp + (size_t)(h0 - MTR) * WW + (w0 - MTC);
        for (int i = tid; i < RH * STq; i += NT) {
            int r = i / STq, q = i - r * STq;
            ST4(&buf0[r * STRD + 4 * q], LD4(base + (size_t)r * WW + 4 * q));
        }
    } else {
        for (int i = tid; i < RH * STRD; i += NT) {
            int r = i / STRD, c = i - r * STRD;
            int gh = h0 - MTR + r, gw = w0 - MTC + c;
            float v = INFINITY;
            if ((unsigned)gh < HH && (unsigned)gw < WW) v = sp[(size_t)gh * WW + gw];
            buf0[r * STRD + c] = v;
        }
    }

    // ---- geometry: 2-row patches; round q handles idx = tid + NT*q
    int pq[2], cq[2], oq[2];
    bool act[2], cen[2];
    float4 s0[2], s1[2];
    float4 p1a[2], p1b[2], p2a[2], p2b[2];   // e_{t-1}, e_{t-2} at own quads
#pragma unroll
    for (int q = 0; q < 2; ++q) {
        int idx = tid + NT * q;
        int p = idx / STq, c = idx - STq * p;
        pq[q] = p; cq[q] = c;
        act[q] = (p < 42) && (c < 22);
        oq[q] = (1 + 2 * p) * STRD + 4 * c;
        cen[q] = act[q] && (p >= 5) && (p <= 36) && (c >= 3) && (c <= 18);
    }
    if (!first) {
#pragma unroll
        for (int q = 0; q < 2; ++q) if (cen[q]) {
            const float* g = skp + (size_t)(h0 + 2 * pq[q] - 10) * WW + (w0 + 4 * cq[q] - 12);
            s0[q] = LD4(g); s1[q] = LD4(g + WW);
        }
    }
    __syncthreads();

    // prev1 = e_0 at own quads (staged values)
#pragma unroll
    for (int q = 0; q < 2; ++q) if (cen[q]) {
        p1a[q] = LD4(buf0 + oq[q]);
        p1b[q] = LD4(buf0 + oq[q] + STRD);
    }

    for (int t = 1; t <= S + 1; ++t) {
        float* sb = ((t - 1) & 1) ? buf1 : buf0;
        float* db = (t & 1) ? buf1 : buf0;
        const bool do_er = (t <= S);
        const bool do_dl = (t >= 2);
        const bool init = (first != 0) && (t == 2);
#pragma unroll
        for (int q = 0; q < 2; ++q) {
            if (!act[q]) continue;
            const bool cw = cen[q] && do_dl;
            if (!(do_er || cw)) continue;
            const int o = oq[q];
            // quad reads from sb (all b128, conflict-free rotations)
            float4 U   = LD4(sb + o - STRD);
            float4 Am0 = LD4(sb + o - 4);
            float4 A0  = LD4(sb + o);
            float4 Ap0 = LD4(sb + o + 4);
            float4 Am1 = LD4(sb + o + STRD - 4);
            float4 A1  = LD4(sb + o + STRD);
            float4 Ap1 = LD4(sb + o + STRD + 4);
            float4 D   = LD4(sb + o + 2 * STRD);
            float4 Um, Up, Dm, Dp;
            if (cw) {   // dilate row -1 / +2 edge quads
                Um = LD4(sb + o - STRD - 4);
                Up = LD4(sb + o - STRD + 4);
                Dm = LD4(sb + o + 2 * STRD - 4);
                Dp = LD4(sb + o + 2 * STRD + 4);
            }
            float4 e0, e1;
            if (do_er) {
                e0 = min4_(min4_(U,  A1), hmin4(Am0.w, A0, Ap0.x));
                e1 = min4_(min4_(A0, D),  hmin4(Am1.w, A1, Ap1.x));
                if (border) {   // force +inf at out-of-image outputs
                    int ghb = h0 - MTR + 1 + 2 * pq[q];
                    int gwb = w0 - MTC + 4 * cq[q];
                    float4 cwm;
                    cwm.x = (unsigned)(gwb + 0) < WW ? -INFINITY : INFINITY;
                    cwm.y = (unsigned)(gwb + 1) < WW ? -INFINITY : INFINITY;
                    cwm.z = (unsigned)(gwb + 2) < WW ? -INFINITY : INFINITY;
                    cwm.w = (unsigned)(gwb + 3) < WW ? -INFINITY : INFINITY;
                    float r0 = (unsigned)ghb       < HH ? -INFINITY : INFINITY;
                    float r1 = (unsigned)(ghb + 1) < HH ? -INFINITY : INFINITY;
                    e0 = max4_(e0, max4_(make_float4(r0, r0, r0, r0), cwm));
                    e1 = max4_(e1, max4_(make_float4(r1, r1, r1, r1), cwm));
                }
                ST4(db + o, e0);
                ST4(db + o + STRD, e1);
            }
            if (cw) {
                float4 tU = U, tA = A0, tB = A1, tD = D;
                float eUm = Um.w, eUp = Up.x, eAm = Am0.w, eAp = Ap0.x;
                float eBm = Am1.w, eBp = Ap1.x, eDm = Dm.w, eDp = Dp.x;
                if (border) {   // mask inputs to -inf outside image
                    int ghb = h0 - MTR + 1 + 2 * pq[q];
                    int gwb = w0 - MTC + 4 * cq[q];
                    float rm0 = (unsigned)(ghb - 1) < HH ? INFINITY : -INFINITY;
                    float rm1 = (unsigned)(ghb)     < HH ? INFINITY : -INFINITY;
                    float rm2 = (unsigned)(ghb + 1) < HH ? INFINITY : -INFINITY;
                    float rm3 = (unsigned)(ghb + 2) < HH ? INFINITY : -INFINITY;
                    float cmL = (unsigned)(gwb - 1) < WW ? INFINITY : -INFINITY;
                    float cmR = (unsigned)(gwb + 4) < WW ? INFINITY : -INFINITY;
                    float4 cmC;
                    cmC.x = (unsigned)(gwb + 0) < WW ? INFINITY : -INFINITY;
                    cmC.y = (unsigned)(gwb + 1) < WW ? INFINITY : -INFINITY;
                    cmC.z = (unsigned)(gwb + 2) < WW ? INFINITY : -INFINITY;
                    cmC.w = (unsigned)(gwb + 3) < WW ? INFINITY : -INFINITY;
                    tU = dmask4(tU, rm0, cmC); tA = dmask4(tA, rm1, cmC);
                    tB = dmask4(tB, rm2, cmC); tD = dmask4(tD, rm3, cmC);
                    eUm = fminf(fminf(eUm, cmL), rm0); eUp = fminf(fminf(eUp, cmR), rm0);
                    eAm = fminf(fminf(eAm, cmL), rm1); eAp = fminf(fminf(eAp, cmR), rm1);
                    eBm = fminf(fminf(eBm, cmL), rm2); eBp = fminf(fminf(eBp, cmR), rm2);
                    eDm = fminf(fminf(eDm, cmL), rm3); eDp = fminf(fminf(eDp, cmR), rm3);
                }
                float4 hU = hmax4(eUm, tU, eUp);
                float4 hA = hmax4(eAm, tA, eAp);
                float4 hB = hmax4(eBm, tB, eBp);
                float4 hD = hmax4(eDm, tD, eDp);
                float4 d0 = max4_(hU, max4_(hA, hB));
                float4 d1 = max4_(hA, max4_(hB, hD));
                skup(s0[q], p2a[q], d0, init);
                skup(s1[q], p2b[q], d1, init);
            }
            if (cen[q] && do_er) {   // rotate register chain
                p2a[q] = p1a[q]; p1a[q] = e0;
                p2b[q] = p1b[q]; p1b[q] = e1;
            }
        }
        __syncthreads();
    }

    // ---- writeback: skel always; e_S (= prev1 regs) if not last phase
#pragma unroll
    for (int q = 0; q < 2; ++q) if (cen[q]) {
        size_t grow = (size_t)(h0 + 2 * pq[q] - 10) * WW + (w0 + 4 * cq[q] - 12);
        ST4(skp + grow, s0[q]);
        ST4(skp + grow + WW, s1[q]);
        if (!last) {
            ST4(dp + grow, p1a[q]);
            ST4(dp + grow + WW, p1b[q]);
        }
    }
}

extern "C" void kernel_launch(void* const* d_in, const int* in_sizes, int n_in,
                              void* d_out, int out_size, void* d_ws, size_t ws_size,
                              hipStream_t stream) {
    const float* img = (const float*)d_in[0];
    float* skel = (float*)d_out;
    const int B = in_sizes[0] / (HH * WW);  // 16
    const size_t plane = (size_t)HH * WW;

    float* e0 = (float*)d_ws;
    float* e1 = e0 + (size_t)B * plane;

    dim3 grid(WW / T, HH / T, B);
    dim3 block(NT);

    const int Ks[5] = {9, 8, 8, 8, 8};   // 41 deltas total (init + 40 iters)
    const float* src = img;
    float* ebufs[2] = {e0, e1};
    for (int p = 0; p < 5; ++p) {
        int first = (p == 0), last = (p == 4);
        float* dstp = last ? nullptr : ebufs[p & 1];
        phase_kernel<<<grid, block, 0, stream>>>(src, dstp, skel, Ks[p], first, last);
        src = dstp;
    }
}